// Round 8
// baseline (217.410 us; speedup 1.0000x reference)
//
#include <hip/hip_runtime.h>
#include <hip/hip_bf16.h>
#include <math.h>

#define N_ATOM   100000
#define N_QUERY  20000
#define KNN      32
#define EDGES    (N_QUERY * KNN)   // 640000

typedef __attribute__((ext_vector_type(8))) short  short8;
typedef __attribute__((ext_vector_type(4))) float  floatx4;
typedef __attribute__((ext_vector_type(2))) float  fx2;

static __device__ __forceinline__ unsigned short f2bf_bits(float f) {
  union { __hip_bfloat16 h; unsigned short u; } cv;
  cv.h = __float2bfloat16(f);
  return cv.u;
}
static __device__ __forceinline__ float bflo(unsigned int u) { return __uint_as_float(u << 16); }
static __device__ __forceinline__ float bfhi(unsigned int u) { return __uint_as_float(u & 0xffff0000u); }

// ---------------- pack weights into MFMA fragment order + precompute edge scores ----------------
// tids [0, 98304): weight packing.  tids [98304, 98304+EDGES): ED[e][h] = edge_attr[e] . Wrbf[h].
__global__ void pack_all_kernel(const float* __restrict__ Wq, const float* __restrict__ Wk,
                                const float* __restrict__ Wv, const float* __restrict__ W1,
                                const float* __restrict__ W2,
                                const float* __restrict__ edge_attr, const float* __restrict__ Wrbf,
                                unsigned short* __restrict__ WKVp, unsigned short* __restrict__ WQp,
                                unsigned short* __restrict__ W1p,  unsigned short* __restrict__ W2p,
                                float* __restrict__ ED) {
  int tid = blockIdx.x * blockDim.x + threadIdx.x;
  if (tid < 98304) {
    const float *Wa, *Wb; int nsplit, Kd, Nd; unsigned short* dst; float scale = 1.0f;
    int t = tid;
    if (t < 32768)      { Wa = Wk; Wb = Wv; nsplit = 128; Kd = 128; Nd = 256; dst = WKVp; }
    else if (t < 49152) { t -= 32768; Wa = Wq; Wb = Wq; nsplit = 128; Kd = 128; Nd = 128; dst = WQp; scale = 0.25f; }
    else if (t < 81920) { t -= 49152; Wa = W1; Wb = W1; nsplit = 128; Kd = 256; Nd = 128; dst = W1p; }
    else                { t -= 81920; Wa = W2; Wb = W2; nsplit = 128; Kd = 128; Nd = 128; dst = W2p; }
    int j    = t & 7;
    int lane = (t >> 3) & 63;
    int t2   = t >> 9;
    int NT   = Nd >> 4;
    int ntile = t2 % NT;
    int ktile = t2 / NT;
    int k = ktile * 32 + (lane >> 4) * 8 + j;
    int n = ntile * 16 + (lane & 15);
    float v = (n < nsplit) ? Wa[(size_t)n * Kd + k] : Wb[(size_t)(n - nsplit) * Kd + k];
    dst[t] = f2bf_bits(v * scale);
  } else {
    int e = tid - 98304;
    if (e >= EDGES) return;
    const float4* ea = (const float4*)(edge_attr + (size_t)e * 16);
    float4 x0 = ea[0], x1 = ea[1], x2 = ea[2], x3 = ea[3];
    float4 r0, r1;
#pragma unroll
    for (int h = 0; h < 8; h++) {
      const float4* wp = (const float4*)(Wrbf + h * 16);
      float4 w0 = wp[0], w1 = wp[1], w2 = wp[2], w3 = wp[3];
      float d = w0.x*x0.x + w0.y*x0.y + w0.z*x0.z + w0.w*x0.w
              + w1.x*x1.x + w1.y*x1.y + w1.z*x1.z + w1.w*x1.w
              + w2.x*x2.x + w2.y*x2.y + w2.z*x2.z + w2.w*x2.w
              + w3.x*x3.x + w3.y*x3.y + w3.z*x3.z + w3.w*x3.w;
      if (h < 4) ((float*)&r0)[h] = d; else ((float*)&r1)[h - 4] = d;
    }
    float4* dst = (float4*)(ED + (size_t)e * 8);
    dst[0] = r0; dst[1] = r1;
  }
}

// ---------------- KV+Q projection: block-specialized persistent GEMM, 4 blocks/CU ----------------
// R2-R7 invariant diagnosis: every pipe <20% busy, occupancy 13.7% (64KB LDS -> 2 blocks/CU).
// Fix the only untested lever: TLP. Blocks specialize: K-blocks stage only the K half of the
// packed KV table (32 KB), V-blocks the V half, Q-blocks the Q table -> 4 blocks/CU, 16 waves/CU.
// acc halves to 8 regs; the 1-deep A-prefetch fits the 128-VGPR budget (~122 live).
// Grid = 464 K + 464 V + 96 Q = 1024 = fully resident; K-block b and V-block b+464 read the
// same h_atom rows concurrently -> L2/L3 dedup on the doubled A-read.
__global__ __launch_bounds__(256, 4) void gemm_kvq(
    const float* __restrict__ h_atom, const float* __restrict__ h_query,
    const unsigned short* __restrict__ WKVp, const unsigned short* __restrict__ WQp,
    unsigned char* __restrict__ Kp8, unsigned char* __restrict__ Vp8,
    unsigned short* __restrict__ Qb) {
  constexpr int KVGROUPS = (N_ATOM + 63) / 64;   // 1563
  constexpr int QGROUPS  = (N_QUERY + 63) / 64;  // 313
  constexpr int NKB = 464, NVB = 464, NQB = 96;  // 1024 total
  __shared__ unsigned short Wlds[16384];         // 32 KB
  const int tid  = threadIdx.x;
  const int l    = tid & 63;
  const int w    = tid >> 6;
  const int quad = l >> 4;
  const int col0 = l & 15;
  const int woff = w * 16 + col0;
  const int bid  = (int)blockIdx.x;

  if (bid < NKB + NVB) {
    const bool isV = bid >= NKB;
    // stage this block's 32-KB weight half: for each ktile (1024 uint4 stride in WKVp),
    // copy 512 uint4 starting at (isV ? 512 : 0).
    {
      const uint4* gsrc = (const uint4*)WKVp;
      uint4* ldst = (uint4*)Wlds;
      const int voff = isV ? 512 : 0;
#pragma unroll
      for (int it = 0; it < 8; it++) {
        int idx = it * 256 + tid;            // 0..2047
        int kt = idx >> 9, wi = idx & 511;
        ldst[idx] = gsrc[kt * 1024 + voff + wi];
      }
    }
    int g = isV ? bid - NKB : bid;
    floatx4 a[8];
    {
      int r = g * 64 + woff; if (r >= N_ATOM) r = N_ATOM - 1;
      const float* ap = h_atom + (size_t)r * 128 + quad * 8;
#pragma unroll
      for (int k0 = 0; k0 < 4; k0++) {
        a[2*k0]   = *(const floatx4*)(ap + k0 * 32);
        a[2*k0+1] = *(const floatx4*)(ap + k0 * 32 + 4);
      }
    }
    __syncthreads();

    unsigned char* Op8 = isV ? Vp8 : Kp8;
    for (; g < KVGROUPS; g += NKB) {
      // 1) issue next group's A loads
      const int gn = g + NKB;
      floatx4 an[8];
#pragma unroll
      for (int i = 0; i < 8; i++) an[i] = (floatx4){0.f, 0.f, 0.f, 0.f};
      if (gn < KVGROUPS) {
        int r = gn * 64 + woff; if (r >= N_ATOM) r = N_ATOM - 1;
        const float* ap = h_atom + (size_t)r * 128 + quad * 8;
#pragma unroll
        for (int k0 = 0; k0 < 4; k0++) {
          an[2*k0]   = *(const floatx4*)(ap + k0 * 32);
          an[2*k0+1] = *(const floatx4*)(ap + k0 * 32 + 4);
        }
      }
      __builtin_amdgcn_sched_barrier(0);

      // 2) convert current A
      short8 af[4];
#pragma unroll
      for (int k0 = 0; k0 < 4; k0++) {
        af[k0][0] = (short)f2bf_bits(a[2*k0][0]);   af[k0][1] = (short)f2bf_bits(a[2*k0][1]);
        af[k0][2] = (short)f2bf_bits(a[2*k0][2]);   af[k0][3] = (short)f2bf_bits(a[2*k0][3]);
        af[k0][4] = (short)f2bf_bits(a[2*k0+1][0]); af[k0][5] = (short)f2bf_bits(a[2*k0+1][1]);
        af[k0][6] = (short)f2bf_bits(a[2*k0+1][2]); af[k0][7] = (short)f2bf_bits(a[2*k0+1][3]);
      }

      // 3) MFMA: 4 ktiles x 8 ntiles from the staged half
      floatx4 acc[8];
#pragma unroll
      for (int i = 0; i < 8; i++) acc[i] = (floatx4){0.f, 0.f, 0.f, 0.f};
#pragma unroll
      for (int k0 = 0; k0 < 4; k0++) {
        const unsigned short* bbase = Wlds + k0 * 4096 + l * 8;
#pragma unroll
        for (int nt = 0; nt < 8; nt++) {
          short8 bf = *(const short8*)(bbase + nt * 512);
          acc[nt] = __builtin_amdgcn_mfma_f32_16x16x32_bf16(bf, af[k0], acc[nt], 0, 0, 0);
        }
      }

      // 4) fp8 pack + stores (this block's 128-channel half)
      const int grow = g * 64 + woff;
      if (grow < N_ATOM) {
        unsigned char* obase = Op8 + (size_t)grow * 128 + quad * 4;
#pragma unroll
        for (int nt = 0; nt < 8; nt++) {
          int pk = __builtin_amdgcn_cvt_pk_fp8_f32(acc[nt][0], acc[nt][1], 0, false);
          pk     = __builtin_amdgcn_cvt_pk_fp8_f32(acc[nt][2], acc[nt][3], pk, true);
          *(int*)(obase + nt * 16) = pk;
        }
      }

      // 5) rotate prefetch
#pragma unroll
      for (int i = 0; i < 8; i++) a[i] = an[i];
    }
  } else {
    // Q blocks
    {
      const uint4* gsrc = (const uint4*)WQp;
      uint4* ldst = (uint4*)Wlds;
#pragma unroll
      for (int it = 0; it < 8; it++) ldst[it * 256 + tid] = gsrc[it * 256 + tid];
    }
    int g = bid - (NKB + NVB);
    floatx4 a[8];
    {
      int r = g * 64 + woff; if (r >= N_QUERY) r = N_QUERY - 1;
      const float* ap = h_query + (size_t)r * 128 + quad * 8;
#pragma unroll
      for (int k0 = 0; k0 < 4; k0++) {
        a[2*k0]   = *(const floatx4*)(ap + k0 * 32);
        a[2*k0+1] = *(const floatx4*)(ap + k0 * 32 + 4);
      }
    }
    __syncthreads();

    for (; g < QGROUPS; g += NQB) {
      const int gn = g + NQB;
      floatx4 an[8];
#pragma unroll
      for (int i = 0; i < 8; i++) an[i] = (floatx4){0.f, 0.f, 0.f, 0.f};
      if (gn < QGROUPS) {
        int r = gn * 64 + woff; if (r >= N_QUERY) r = N_QUERY - 1;
        const float* ap = h_query + (size_t)r * 128 + quad * 8;
#pragma unroll
        for (int k0 = 0; k0 < 4; k0++) {
          an[2*k0]   = *(const floatx4*)(ap + k0 * 32);
          an[2*k0+1] = *(const floatx4*)(ap + k0 * 32 + 4);
        }
      }
      __builtin_amdgcn_sched_barrier(0);

      short8 af[4];
#pragma unroll
      for (int k0 = 0; k0 < 4; k0++) {
        af[k0][0] = (short)f2bf_bits(a[2*k0][0]);   af[k0][1] = (short)f2bf_bits(a[2*k0][1]);
        af[k0][2] = (short)f2bf_bits(a[2*k0][2]);   af[k0][3] = (short)f2bf_bits(a[2*k0][3]);
        af[k0][4] = (short)f2bf_bits(a[2*k0+1][0]); af[k0][5] = (short)f2bf_bits(a[2*k0+1][1]);
        af[k0][6] = (short)f2bf_bits(a[2*k0+1][2]); af[k0][7] = (short)f2bf_bits(a[2*k0+1][3]);
      }

      floatx4 acc[8];
#pragma unroll
      for (int i = 0; i < 8; i++) acc[i] = (floatx4){0.f, 0.f, 0.f, 0.f};
#pragma unroll
      for (int k0 = 0; k0 < 4; k0++) {
        const unsigned short* bbase = Wlds + k0 * 4096 + l * 8;
#pragma unroll
        for (int nt = 0; nt < 8; nt++) {
          short8 bf = *(const short8*)(bbase + nt * 512);
          acc[nt] = __builtin_amdgcn_mfma_f32_16x16x32_bf16(bf, af[k0], acc[nt], 0, 0, 0);
        }
      }

      const int grow = g * 64 + woff;
      if (grow < N_QUERY) {
#pragma unroll
        for (int nt = 0; nt < 8; nt++) {
          unsigned u0 = (unsigned)f2bf_bits(acc[nt][0]) | ((unsigned)f2bf_bits(acc[nt][1]) << 16);
          unsigned u1 = (unsigned)f2bf_bits(acc[nt][2]) | ((unsigned)f2bf_bits(acc[nt][3]) << 16);
          uint2 uu; uu.x = u0; uu.y = u1;
          *(uint2*)(Qb + (size_t)grow * 128 + nt * 16 + quad * 4) = uu;
        }
      }

#pragma unroll
      for (int i = 0; i < 8; i++) a[i] = an[i];
    }
  }
}

// ---------------- attention: minimal live set, all gathers in one latency window ----------------
__global__ __launch_bounds__(256, 4) void attn_kernel(
    const unsigned short* __restrict__ Qb,    // [N_QUERY][128] bf16 (pre-scaled 1/sqrt(16))
    const unsigned char* __restrict__ Kp8,    // [N_ATOM][128] fp8 e4m3
    const unsigned char* __restrict__ Vp8,    // [N_ATOM][128] fp8 e4m3
    const float* __restrict__ ED,             // [E][8] precomputed edge scores
    const int* __restrict__ src,              // [E]
    float* __restrict__ Agg) {                // [N_QUERY][128]
  const int l = threadIdx.x & 63;
  const int w = threadIdx.x >> 6;
  const int q = blockIdx.x * 4 + w;
  const int j = l >> 3;
  const int h = l & 7;
  const int e0 = q * KNN;

  int s0 = src[e0 +  0 + j];
  int s1 = src[e0 +  8 + j];
  int s2 = src[e0 + 16 + j];
  int s3 = src[e0 + 24 + j];

  const float* edp = ED + (size_t)e0 * 8 + l;
  float ed0 = edp[0];
  float ed1 = edp[64];
  float ed2 = edp[128];
  float ed3 = edp[192];

  const uint4* qp = (const uint4*)(Qb + (size_t)q * 128 + h * 16);
  uint4 qA = qp[0], qB = qp[1];

  uint4 kq0 = *(const uint4*)(Kp8 + (size_t)s0 * 128 + h * 16);
  uint4 kq1 = *(const uint4*)(Kp8 + (size_t)s1 * 128 + h * 16);
  uint4 kq2 = *(const uint4*)(Kp8 + (size_t)s2 * 128 + h * 16);
  uint4 kq3 = *(const uint4*)(Kp8 + (size_t)s3 * 128 + h * 16);
  uint4 vq0 = *(const uint4*)(Vp8 + (size_t)s0 * 128 + h * 16);
  uint4 vq1 = *(const uint4*)(Vp8 + (size_t)s1 * 128 + h * 16);
  uint4 vq2 = *(const uint4*)(Vp8 + (size_t)s2 * 128 + h * 16);
  uint4 vq3 = *(const uint4*)(Vp8 + (size_t)s3 * 128 + h * 16);

  float qd[16];
  qd[0]  = bflo(qA.x); qd[1]  = bfhi(qA.x); qd[2]  = bflo(qA.y); qd[3]  = bfhi(qA.y);
  qd[4]  = bflo(qA.z); qd[5]  = bfhi(qA.z); qd[6]  = bflo(qA.w); qd[7]  = bfhi(qA.w);
  qd[8]  = bflo(qB.x); qd[9]  = bfhi(qB.x); qd[10] = bflo(qB.y); qd[11] = bfhi(qB.y);
  qd[12] = bflo(qB.z); qd[13] = bfhi(qB.z); qd[14] = bflo(qB.w); qd[15] = bfhi(qB.w);

  float acc[16];
#pragma unroll
  for (int i = 0; i < 16; i++) acc[i] = 0.f;
  float lsum = 0.f;

  auto dopass = [&](const uint4& kq, const uint4& vq, float ed) {
    float kd = 0.f;
    {
      fx2 f0, f1;
      f0 = __builtin_amdgcn_cvt_pk_f32_fp8((int)kq.x, false);
      f1 = __builtin_amdgcn_cvt_pk_f32_fp8((int)kq.x, true);
      kd += qd[0] * f0[0] + qd[1] * f0[1] + qd[2] * f1[0] + qd[3] * f1[1];
      f0 = __builtin_amdgcn_cvt_pk_f32_fp8((int)kq.y, false);
      f1 = __builtin_amdgcn_cvt_pk_f32_fp8((int)kq.y, true);
      kd += qd[4] * f0[0] + qd[5] * f0[1] + qd[6] * f1[0] + qd[7] * f1[1];
      f0 = __builtin_amdgcn_cvt_pk_f32_fp8((int)kq.z, false);
      f1 = __builtin_amdgcn_cvt_pk_f32_fp8((int)kq.z, true);
      kd += qd[8] * f0[0] + qd[9] * f0[1] + qd[10] * f1[0] + qd[11] * f1[1];
      f0 = __builtin_amdgcn_cvt_pk_f32_fp8((int)kq.w, false);
      f1 = __builtin_amdgcn_cvt_pk_f32_fp8((int)kq.w, true);
      kd += qd[12] * f0[0] + qd[13] * f0[1] + qd[14] * f1[0] + qd[15] * f1[1];
    }
    float pe = __expf(kd + ed);
    lsum += pe;
    {
      fx2 g0, g1;
      g0 = __builtin_amdgcn_cvt_pk_f32_fp8((int)vq.x, false);
      g1 = __builtin_amdgcn_cvt_pk_f32_fp8((int)vq.x, true);
      acc[0] += pe * g0[0]; acc[1] += pe * g0[1]; acc[2] += pe * g1[0]; acc[3] += pe * g1[1];
      g0 = __builtin_amdgcn_cvt_pk_f32_fp8((int)vq.y, false);
      g1 = __builtin_amdgcn_cvt_pk_f32_fp8((int)vq.y, true);
      acc[4] += pe * g0[0]; acc[5] += pe * g0[1]; acc[6] += pe * g1[0]; acc[7] += pe * g1[1];
      g0 = __builtin_amdgcn_cvt_pk_f32_fp8((int)vq.z, false);
      g1 = __builtin_amdgcn_cvt_pk_f32_fp8((int)vq.z, true);
      acc[8] += pe * g0[0]; acc[9] += pe * g0[1]; acc[10] += pe * g1[0]; acc[11] += pe * g1[1];
      g0 = __builtin_amdgcn_cvt_pk_f32_fp8((int)vq.w, false);
      g1 = __builtin_amdgcn_cvt_pk_f32_fp8((int)vq.w, true);
      acc[12] += pe * g0[0]; acc[13] += pe * g0[1]; acc[14] += pe * g1[0]; acc[15] += pe * g1[1];
    }
  };
  dopass(kq0, vq0, ed0);
  dopass(kq1, vq1, ed1);
  dopass(kq2, vq2, ed2);
  dopass(kq3, vq3, ed3);

  lsum += __shfl_xor(lsum, 8, 64);
  lsum += __shfl_xor(lsum, 16, 64);
  lsum += __shfl_xor(lsum, 32, 64);

  float r8[8];
  const bool hiA = (l & 32) != 0;
#pragma unroll
  for (int i = 0; i < 8; i++) {
    float keep = hiA ? acc[i + 8] : acc[i];
    float send = hiA ? acc[i]     : acc[i + 8];
    r8[i] = keep + __shfl_xor(send, 32, 64);
  }
  float r4[4];
  const bool hiB = (l & 16) != 0;
#pragma unroll
  for (int i = 0; i < 4; i++) {
    float keep = hiB ? r8[i + 4] : r8[i];
    float send = hiB ? r8[i]     : r8[i + 4];
    r4[i] = keep + __shfl_xor(send, 16, 64);
  }
  float r2[2];
  const bool hiC = (l & 8) != 0;
#pragma unroll
  for (int i = 0; i < 2; i++) {
    float keep = hiC ? r4[i + 2] : r4[i];
    float send = hiC ? r4[i]     : r4[i + 2];
    r2[i] = keep + __shfl_xor(send, 8, 64);
  }
  float inv = 1.f / (lsum + 1e-16f);
  float2 o; o.x = r2[0] * inv; o.y = r2[1] * inv;
  *(float2*)(Agg + (size_t)q * 128 + h * 16 + 2 * j) = o;
}

// ---------------- fused MLP: LDS-staged weights (rotating 32KB), A prefetched upfront ----------
__global__ __launch_bounds__(256, 1) void mlp_kernel(
    const float* __restrict__ h_query, const float* __restrict__ Agg,
    const unsigned short* __restrict__ W1p, const unsigned short* __restrict__ W2p,
    const float* __restrict__ b1, const float* __restrict__ b2,
    const float* __restrict__ gamma, const float* __restrict__ beta,
    float* __restrict__ out) {
  constexpr int M = N_QUERY;
  constexpr int STRIDE = 136;                  // ushorts per hid row (272 B)
  __shared__ unsigned short Wlds[16384];       // 32 KB rotating weight stage
  __shared__ unsigned short hid[64 * STRIDE];  // 17.4 KB hidden activations

  const int tid  = threadIdx.x;
  const int l    = tid & 63;
  const int w    = tid >> 6;
  const int quad = l >> 4;
  const int col0 = l & 15;
  const int row0 = blockIdx.x * 64 + w * 16;
  const int grow = row0 + col0;
  const int arow = grow < M ? grow : M - 1;

  // 1) issue BOTH A-rows first: h_query (tiles 0..3) + Agg (tiles 4..7), 16 float4 in flight
  const float* hp = h_query + (size_t)arow * 128 + quad * 8;
  const float* gp = Agg     + (size_t)arow * 128 + quad * 8;
  floatx4 a[16];
#pragma unroll
  for (int k0 = 0; k0 < 4; k0++) {
    a[2*k0]       = *(const floatx4*)(hp + k0 * 32);
    a[2*k0+1]     = *(const floatx4*)(hp + k0 * 32 + 4);
    a[8 + 2*k0]   = *(const floatx4*)(gp + k0 * 32);
    a[8 + 2*k0+1] = *(const floatx4*)(gp + k0 * 32 + 4);
  }

  // 2) stage W1 k-tiles 0..3 (k0 < 128): 32 KB coalesced
  {
    const uint4* gsrc = (const uint4*)W1p;
    uint4* ldst = (uint4*)Wlds;
#pragma unroll
    for (int it = 0; it < 8; it++) ldst[it * 256 + tid] = gsrc[it * 256 + tid];
  }

  // 3) convert A to bf16 fragments (waits only on A loads)
  short8 af[8];
#pragma unroll
  for (int t = 0; t < 8; t++) {
    af[t][0] = (short)f2bf_bits(a[2*t][0]);   af[t][1] = (short)f2bf_bits(a[2*t][1]);
    af[t][2] = (short)f2bf_bits(a[2*t][2]);   af[t][3] = (short)f2bf_bits(a[2*t][3]);
    af[t][4] = (short)f2bf_bits(a[2*t+1][0]); af[t][5] = (short)f2bf_bits(a[2*t+1][1]);
    af[t][6] = (short)f2bf_bits(a[2*t+1][2]); af[t][7] = (short)f2bf_bits(a[2*t+1][3]);
  }
  __syncthreads();

  // 4) GEMM1 first half (k0 < 128)
  floatx4 acc[8];
#pragma unroll
  for (int i = 0; i < 8; i++) acc[i] = (floatx4){0.f, 0.f, 0.f, 0.f};
#pragma unroll
  for (int kt = 0; kt < 4; kt++) {
    const unsigned short* bbase = Wlds + kt * 4096 + l * 8;
#pragma unroll
    for (int nt = 0; nt < 8; nt++) {
      short8 bf = *(const short8*)(bbase + nt * 512);
      acc[nt] = __builtin_amdgcn_mfma_f32_16x16x32_bf16(bf, af[kt], acc[nt], 0, 0, 0);
    }
  }
  __syncthreads();

  // 5) stage W1 k-tiles 4..7 (k0 >= 128)
  {
    const uint4* gsrc = (const uint4*)(W1p + 16384);
    uint4* ldst = (uint4*)Wlds;
#pragma unroll
    for (int it = 0; it < 8; it++) ldst[it * 256 + tid] = gsrc[it * 256 + tid];
  }
  __syncthreads();

  // 6) GEMM1 second half
#pragma unroll
  for (int kt = 0; kt < 4; kt++) {
    const unsigned short* bbase = Wlds + kt * 4096 + l * 8;
#pragma unroll
    for (int nt = 0; nt < 8; nt++) {
      short8 bf = *(const short8*)(bbase + nt * 512);
      acc[nt] = __builtin_amdgcn_mfma_f32_16x16x32_bf16(bf, af[4 + kt], acc[nt], 0, 0, 0);
    }
  }

  // 7) hidden -> LDS (bias + relu, bf16, 8-B stores)
  {
    const int rl = w * 16 + col0;
#pragma unroll
    for (int nt = 0; nt < 8; nt++) {
      const int c = nt * 16 + quad * 4;
      float4 bb = *(const float4*)(b1 + c);
      unsigned u0 = (unsigned)f2bf_bits(fmaxf(acc[nt][0] + bb.x, 0.f))
                  | ((unsigned)f2bf_bits(fmaxf(acc[nt][1] + bb.y, 0.f)) << 16);
      unsigned u1 = (unsigned)f2bf_bits(fmaxf(acc[nt][2] + bb.z, 0.f))
                  | ((unsigned)f2bf_bits(fmaxf(acc[nt][3] + bb.w, 0.f)) << 16);
      uint2 uu; uu.x = u0; uu.y = u1;
      *(uint2*)(hid + rl * STRIDE + c) = uu;
    }
  }
  __syncthreads();

  // 8) stage W2 (32 KB)
  {
    const uint4* gsrc = (const uint4*)W2p;
    uint4* ldst = (uint4*)Wlds;
#pragma unroll
    for (int it = 0; it < 8; it++) ldst[it * 256 + tid] = gsrc[it * 256 + tid];
  }
  __syncthreads();

  // 9) GEMM2 (K=128), A from hid, B from Wlds
  floatx4 acc2[8];
#pragma unroll
  for (int i = 0; i < 8; i++) acc2[i] = (floatx4){0.f, 0.f, 0.f, 0.f};
  const int rloc = w * 16 + col0;
#pragma unroll
  for (int k0 = 0; k0 < 128; k0 += 32) {
    short8 af2 = *(const short8*)(hid + rloc * STRIDE + k0 + quad * 8);
    const unsigned short* bbase = Wlds + (k0 >> 5) * 4096 + l * 8;
#pragma unroll
    for (int nt = 0; nt < 8; nt++) {
      short8 bf = *(const short8*)(bbase + nt * 512);
      acc2[nt] = __builtin_amdgcn_mfma_f32_16x16x32_bf16(bf, af2, acc2[nt], 0, 0, 0);
    }
  }

  // 10) residual + LayerNorm: lane owns 32 channels of ONE row, reduce over quad
  const int rr = grow < M ? grow : M - 1;
  float v[8][4];
  float s1 = 0.f, s2 = 0.f;
#pragma unroll
  for (int nt = 0; nt < 8; nt++) {
    const int c = nt * 16 + quad * 4;
    float4 hq = *(const float4*)(h_query + (size_t)rr * 128 + c);
    float4 bb = *(const float4*)(b2 + c);
    float t0 = acc2[nt][0] + bb.x + hq.x;
    float t1 = acc2[nt][1] + bb.y + hq.y;
    float t2 = acc2[nt][2] + bb.z + hq.z;
    float t3 = acc2[nt][3] + bb.w + hq.w;
    v[nt][0] = t0; v[nt][1] = t1; v[nt][2] = t2; v[nt][3] = t3;
    s1 += t0 + t1 + t2 + t3;
    s2 += t0 * t0 + t1 * t1 + t2 * t2 + t3 * t3;
  }
  s1 += __shfl_xor(s1, 16, 64); s1 += __shfl_xor(s1, 32, 64);
  s2 += __shfl_xor(s2, 16, 64); s2 += __shfl_xor(s2, 32, 64);
  float mean = s1 * (1.0f / 128.0f);
  float var  = s2 * (1.0f / 128.0f) - mean * mean;
  float rstd = rsqrtf(var + 1e-5f);
  if (grow < M) {
#pragma unroll
    for (int nt = 0; nt < 8; nt++) {
      const int c = nt * 16 + quad * 4;
      float4 gg = *(const float4*)(gamma + c);
      float4 be = *(const float4*)(beta + c);
      float4 o;
      o.x = (v[nt][0] - mean) * rstd * gg.x + be.x;
      o.y = (v[nt][1] - mean) * rstd * gg.y + be.y;
      o.z = (v[nt][2] - mean) * rstd * gg.z + be.z;
      o.w = (v[nt][3] - mean) * rstd * gg.w + be.w;
      *(float4*)(out + (size_t)grow * 128 + c) = o;
    }
  }
}

extern "C" void kernel_launch(void* const* d_in, const int* in_sizes, int n_in,
                              void* d_out, int out_size, void* d_ws, size_t ws_size,
                              hipStream_t stream) {
  const float* h_atom    = (const float*)d_in[0];
  const float* h_query   = (const float*)d_in[1];
  const float* edge_attr = (const float*)d_in[2];
  const float* W_q  = (const float*)d_in[3];
  const float* W_k  = (const float*)d_in[4];
  const float* W_v  = (const float*)d_in[5];
  const float* Wrbf = (const float*)d_in[6];
  const float* W1   = (const float*)d_in[7];
  const float* b1   = (const float*)d_in[8];
  const float* W2   = (const float*)d_in[9];
  const float* b2   = (const float*)d_in[10];
  const float* ln_g = (const float*)d_in[11];
  const float* ln_b = (const float*)d_in[12];
  const int* edge_index = (const int*)d_in[13];   // [0..E) = src
  float* out = (float*)d_out;

  char* ws = (char*)d_ws;
  unsigned char*  Kp8 = (unsigned char*)(ws);                  // 100000*128 B = 12.8 MB
  unsigned char*  Vp8 = (unsigned char*)(ws + 12800000);       // 100000*128 B = 12.8 MB
  unsigned short* Qb  = (unsigned short*)(ws + 25600000);      // 20000*128 bf16 = 5.12 MB
  float* Agg          = (float*)(ws + 30720000);               // 20000*128 f32  = 10.24 MB
  unsigned short* WKVp = (unsigned short*)(ws + 40960000);     // 128x256
  unsigned short* WQp  = WKVp + 32768;                         // 128x128
  unsigned short* W1p  = WQp  + 16384;                         // 256x128
  unsigned short* W2p  = W1p  + 32768;                         // 128x128
  float* ED           = (float*)(ws + 41160704);               // 640000*8 f32 = 20.48 MB

  // pack weights + precompute per-edge attention bias ED = edge_attr @ Wrbf^T
  pack_all_kernel<<<(98304 + EDGES + 255) / 256, 256, 0, stream>>>(
      W_q, W_k, W_v, W1, W2, edge_attr, Wrbf, WKVp, WQp, W1p, W2p, ED);

  // block-specialized persistent GEMM: 464 K + 464 V + 96 Q blocks (4 blocks/CU)
  gemm_kvq<<<1024, 256, 0, stream>>>(h_atom, h_query, WKVp, WQp, Kp8, Vp8, Qb);

  // attention -> Agg
  attn_kernel<<<N_QUERY / 4, 256, 0, stream>>>(Qb, Kp8, Vp8, ED, edge_index, Agg);

  // fused MLP + residual + LayerNorm -> out
  mlp_kernel<<<(N_QUERY + 63) / 64, 256, 0, stream>>>(
      h_query, Agg, W1p, W2p, b1, b2, ln_g, ln_b, out);
}

// Round 9
// 205.244 us; speedup vs baseline: 1.0593x; 1.0593x over previous
//
#include <hip/hip_runtime.h>
#include <hip/hip_bf16.h>
#include <math.h>

#define N_ATOM   100000
#define N_QUERY  20000
#define KNN      32
#define EDGES    (N_QUERY * KNN)   // 640000

typedef __attribute__((ext_vector_type(8))) short  short8;
typedef __attribute__((ext_vector_type(4))) float  floatx4;
typedef __attribute__((ext_vector_type(2))) float  fx2;

static __device__ __forceinline__ unsigned short f2bf_bits(float f) {
  union { __hip_bfloat16 h; unsigned short u; } cv;
  cv.h = __float2bfloat16(f);
  return cv.u;
}
static __device__ __forceinline__ float bflo(unsigned int u) { return __uint_as_float(u << 16); }
static __device__ __forceinline__ float bfhi(unsigned int u) { return __uint_as_float(u & 0xffff0000u); }

// ---------------- pack weights into MFMA fragment order (weights only now) ----------------
__global__ void pack_all_kernel(const float* __restrict__ Wq, const float* __restrict__ Wk,
                                const float* __restrict__ Wv, const float* __restrict__ W1,
                                const float* __restrict__ W2,
                                unsigned short* __restrict__ WKVp, unsigned short* __restrict__ WQp,
                                unsigned short* __restrict__ W1p,  unsigned short* __restrict__ W2p) {
  int tid = blockIdx.x * blockDim.x + threadIdx.x;
  if (tid >= 98304) return;
  const float *Wa, *Wb; int nsplit, Kd, Nd; unsigned short* dst; float scale = 1.0f;
  int t = tid;
  if (t < 32768)      { Wa = Wk; Wb = Wv; nsplit = 128; Kd = 128; Nd = 256; dst = WKVp; }
  else if (t < 49152) { t -= 32768; Wa = Wq; Wb = Wq; nsplit = 128; Kd = 128; Nd = 128; dst = WQp; scale = 0.25f; }
  else if (t < 81920) { t -= 49152; Wa = W1; Wb = W1; nsplit = 128; Kd = 256; Nd = 128; dst = W1p; }
  else                { t -= 81920; Wa = W2; Wb = W2; nsplit = 128; Kd = 128; Nd = 128; dst = W2p; }
  int j    = t & 7;
  int lane = (t >> 3) & 63;
  int t2   = t >> 9;
  int NT   = Nd >> 4;
  int ntile = t2 % NT;
  int ktile = t2 / NT;
  int k = ktile * 32 + (lane >> 4) * 8 + j;
  int n = ntile * 16 + (lane & 15);
  float v = (n < nsplit) ? Wa[(size_t)n * Kd + k] : Wb[(size_t)(n - nsplit) * Kd + k];
  dst[t] = f2bf_bits(v * scale);
}

// ---------------- merged KV+Q projection GEMM + ED streaming blocks ----------------
// KV/Q paths: R5's best-measured structure (weights staged in LDS once per block).
// ED blocks (bid >= KB+QB): no LDS, pure streaming ED[e][h] = edge_attr[e].Wrbf[h] —
// they soak up the CU slack the latency-bound KV blocks leave (<25% pipe utilization),
// eliminating the serialized ED tail that used to live in pack_all.
__global__ __launch_bounds__(256, 2) void gemm_kvq(
    const float* __restrict__ h_atom, const float* __restrict__ h_query,
    const unsigned short* __restrict__ WKVp, const unsigned short* __restrict__ WQp,
    const float* __restrict__ edge_attr, const float* __restrict__ Wrbf,
    unsigned char* __restrict__ Kp8, unsigned char* __restrict__ Vp8,
    unsigned short* __restrict__ Qb, float* __restrict__ ED) {
  constexpr int KB  = (N_ATOM + 63) / 64;    // 1563
  constexpr int QB  = (N_QUERY + 63) / 64;   // 313
  constexpr int EDB = 1280;
  __shared__ unsigned short Wlds[32768];     // 64 KB: KV uses all, Q uses first 32 KB
  const int tid  = threadIdx.x;
  const int l    = tid & 63;
  const int w    = tid >> 6;
  const int quad = l >> 4;
  const int col0 = l & 15;
  const int bid  = (int)blockIdx.x;

  if (bid < KB) {
    const int row0 = bid * 64 + w * 16;
    const int grow = row0 + col0;
    int arow = grow < N_ATOM ? grow : N_ATOM - 1;

    // 1) issue A-row loads first (HBM, long latency)
    const float* aptr = h_atom + (size_t)arow * 128 + quad * 8;
    floatx4 a[8];
#pragma unroll
    for (int k0 = 0; k0 < 4; k0++) {
      a[2 * k0]     = *(const floatx4*)(aptr + k0 * 32);
      a[2 * k0 + 1] = *(const floatx4*)(aptr + k0 * 32 + 4);
    }
    // 2) stage the 64 KB weight table into LDS
    {
      const uint4* gsrc = (const uint4*)WKVp;
      uint4* ldst = (uint4*)Wlds;
#pragma unroll
      for (int it = 0; it < 16; it++)
        ldst[it * 256 + tid] = gsrc[it * 256 + tid];
    }
    // 3) convert A
    short8 af[4];
#pragma unroll
    for (int k0 = 0; k0 < 4; k0++) {
      af[k0][0] = (short)f2bf_bits(a[2*k0][0]); af[k0][1] = (short)f2bf_bits(a[2*k0][1]);
      af[k0][2] = (short)f2bf_bits(a[2*k0][2]); af[k0][3] = (short)f2bf_bits(a[2*k0][3]);
      af[k0][4] = (short)f2bf_bits(a[2*k0+1][0]); af[k0][5] = (short)f2bf_bits(a[2*k0+1][1]);
      af[k0][6] = (short)f2bf_bits(a[2*k0+1][2]); af[k0][7] = (short)f2bf_bits(a[2*k0+1][3]);
    }
    __syncthreads();

    // 4) MFMA loop, B from LDS
    floatx4 acc[16];
#pragma unroll
    for (int i = 0; i < 16; i++) acc[i] = (floatx4){0.f, 0.f, 0.f, 0.f};
#pragma unroll
    for (int k0 = 0; k0 < 4; k0++) {
      const unsigned short* bbase = Wlds + k0 * 16 * 512 + l * 8;
#pragma unroll
      for (int nt = 0; nt < 16; nt++) {
        short8 bf = *(const short8*)(bbase + nt * 512);
        acc[nt] = __builtin_amdgcn_mfma_f32_16x16x32_bf16(bf, af[k0], acc[nt], 0, 0, 0);
      }
    }
    // 5) fp8 pack + direct global stores
    if (grow < N_ATOM) {
      unsigned char* kbase = Kp8 + (size_t)grow * 128 + quad * 4;
      unsigned char* vbase = Vp8 + (size_t)grow * 128 + quad * 4;
#pragma unroll
      for (int nt = 0; nt < 16; nt++) {
        int pk = __builtin_amdgcn_cvt_pk_fp8_f32(acc[nt][0], acc[nt][1], 0, false);
        pk     = __builtin_amdgcn_cvt_pk_fp8_f32(acc[nt][2], acc[nt][3], pk, true);
        if (nt < 8) *(int*)(kbase + nt * 16) = pk;
        else        *(int*)(vbase + (nt - 8) * 16) = pk;
      }
    }
  } else if (bid < KB + QB) {
    const int row0 = (bid - KB) * 64 + w * 16;
    const int grow = row0 + col0;
    int arow = grow < N_QUERY ? grow : N_QUERY - 1;

    const float* aptr = h_query + (size_t)arow * 128 + quad * 8;
    floatx4 a[8];
#pragma unroll
    for (int k0 = 0; k0 < 4; k0++) {
      a[2 * k0]     = *(const floatx4*)(aptr + k0 * 32);
      a[2 * k0 + 1] = *(const floatx4*)(aptr + k0 * 32 + 4);
    }
    {
      const uint4* gsrc = (const uint4*)WQp;
      uint4* ldst = (uint4*)Wlds;
#pragma unroll
      for (int it = 0; it < 8; it++)
        ldst[it * 256 + tid] = gsrc[it * 256 + tid];
    }
    short8 af[4];
#pragma unroll
    for (int k0 = 0; k0 < 4; k0++) {
      af[k0][0] = (short)f2bf_bits(a[2*k0][0]); af[k0][1] = (short)f2bf_bits(a[2*k0][1]);
      af[k0][2] = (short)f2bf_bits(a[2*k0][2]); af[k0][3] = (short)f2bf_bits(a[2*k0][3]);
      af[k0][4] = (short)f2bf_bits(a[2*k0+1][0]); af[k0][5] = (short)f2bf_bits(a[2*k0+1][1]);
      af[k0][6] = (short)f2bf_bits(a[2*k0+1][2]); af[k0][7] = (short)f2bf_bits(a[2*k0+1][3]);
    }
    __syncthreads();

    floatx4 acc[8];
#pragma unroll
    for (int i = 0; i < 8; i++) acc[i] = (floatx4){0.f, 0.f, 0.f, 0.f};
#pragma unroll
    for (int k0 = 0; k0 < 4; k0++) {
      const unsigned short* bbase = Wlds + k0 * 8 * 512 + l * 8;
#pragma unroll
      for (int nt = 0; nt < 8; nt++) {
        short8 bf = *(const short8*)(bbase + nt * 512);
        acc[nt] = __builtin_amdgcn_mfma_f32_16x16x32_bf16(bf, af[k0], acc[nt], 0, 0, 0);
      }
    }
    if (grow < N_QUERY) {
#pragma unroll
      for (int nt = 0; nt < 8; nt++) {
        unsigned u0 = (unsigned)f2bf_bits(acc[nt][0]) | ((unsigned)f2bf_bits(acc[nt][1]) << 16);
        unsigned u1 = (unsigned)f2bf_bits(acc[nt][2]) | ((unsigned)f2bf_bits(acc[nt][3]) << 16);
        uint2 uu; uu.x = u0; uu.y = u1;
        *(uint2*)(Qb + (size_t)grow * 128 + nt * 16 + quad * 4) = uu;
      }
    }
  } else {
    // ED streaming blocks: grid-stride over edges, 2 iterations
    int e = (bid - (KB + QB)) * 256 + tid;
#pragma unroll
    for (int it = 0; it < 2; it++, e += EDB * 256) {
      if (e < EDGES) {
        const float4* ea = (const float4*)(edge_attr + (size_t)e * 16);
        float4 x0 = ea[0], x1 = ea[1], x2 = ea[2], x3 = ea[3];
        float4 r0, r1;
#pragma unroll
        for (int h = 0; h < 8; h++) {
          const float4* wp = (const float4*)(Wrbf + h * 16);
          float4 w0 = wp[0], w1 = wp[1], w2 = wp[2], w3 = wp[3];
          float d = w0.x*x0.x + w0.y*x0.y + w0.z*x0.z + w0.w*x0.w
                  + w1.x*x1.x + w1.y*x1.y + w1.z*x1.z + w1.w*x1.w
                  + w2.x*x2.x + w2.y*x2.y + w2.z*x2.z + w2.w*x2.w
                  + w3.x*x3.x + w3.y*x3.y + w3.z*x3.z + w3.w*x3.w;
          if (h < 4) ((float*)&r0)[h] = d; else ((float*)&r1)[h - 4] = d;
        }
        float4* dst = (float4*)(ED + (size_t)e * 8);
        dst[0] = r0; dst[1] = r1;
      }
    }
  }
}

// ---------------- attention: bf16 Agg output (halves roundtrip traffic) ----------------
__global__ __launch_bounds__(256, 4) void attn_kernel(
    const unsigned short* __restrict__ Qb,    // [N_QUERY][128] bf16 (pre-scaled 1/sqrt(16))
    const unsigned char* __restrict__ Kp8,    // [N_ATOM][128] fp8 e4m3
    const unsigned char* __restrict__ Vp8,    // [N_ATOM][128] fp8 e4m3
    const float* __restrict__ ED,             // [E][8] precomputed edge scores
    const int* __restrict__ src,              // [E]
    unsigned short* __restrict__ Agg16) {     // [N_QUERY][128] bf16
  const int l = threadIdx.x & 63;
  const int w = threadIdx.x >> 6;
  const int q = blockIdx.x * 4 + w;
  const int j = l >> 3;
  const int h = l & 7;
  const int e0 = q * KNN;

  int s0 = src[e0 +  0 + j];
  int s1 = src[e0 +  8 + j];
  int s2 = src[e0 + 16 + j];
  int s3 = src[e0 + 24 + j];

  const float* edp = ED + (size_t)e0 * 8 + l;
  float ed0 = edp[0];
  float ed1 = edp[64];
  float ed2 = edp[128];
  float ed3 = edp[192];

  const uint4* qp = (const uint4*)(Qb + (size_t)q * 128 + h * 16);
  uint4 qA = qp[0], qB = qp[1];

  uint4 kq0 = *(const uint4*)(Kp8 + (size_t)s0 * 128 + h * 16);
  uint4 kq1 = *(const uint4*)(Kp8 + (size_t)s1 * 128 + h * 16);
  uint4 kq2 = *(const uint4*)(Kp8 + (size_t)s2 * 128 + h * 16);
  uint4 kq3 = *(const uint4*)(Kp8 + (size_t)s3 * 128 + h * 16);
  uint4 vq0 = *(const uint4*)(Vp8 + (size_t)s0 * 128 + h * 16);
  uint4 vq1 = *(const uint4*)(Vp8 + (size_t)s1 * 128 + h * 16);
  uint4 vq2 = *(const uint4*)(Vp8 + (size_t)s2 * 128 + h * 16);
  uint4 vq3 = *(const uint4*)(Vp8 + (size_t)s3 * 128 + h * 16);

  float qd[16];
  qd[0]  = bflo(qA.x); qd[1]  = bfhi(qA.x); qd[2]  = bflo(qA.y); qd[3]  = bfhi(qA.y);
  qd[4]  = bflo(qA.z); qd[5]  = bfhi(qA.z); qd[6]  = bflo(qA.w); qd[7]  = bfhi(qA.w);
  qd[8]  = bflo(qB.x); qd[9]  = bfhi(qB.x); qd[10] = bflo(qB.y); qd[11] = bfhi(qB.y);
  qd[12] = bflo(qB.z); qd[13] = bfhi(qB.z); qd[14] = bflo(qB.w); qd[15] = bfhi(qB.w);

  float acc[16];
#pragma unroll
  for (int i = 0; i < 16; i++) acc[i] = 0.f;
  float lsum = 0.f;

  auto dopass = [&](const uint4& kq, const uint4& vq, float ed) {
    float kd = 0.f;
    {
      fx2 f0, f1;
      f0 = __builtin_amdgcn_cvt_pk_f32_fp8((int)kq.x, false);
      f1 = __builtin_amdgcn_cvt_pk_f32_fp8((int)kq.x, true);
      kd += qd[0] * f0[0] + qd[1] * f0[1] + qd[2] * f1[0] + qd[3] * f1[1];
      f0 = __builtin_amdgcn_cvt_pk_f32_fp8((int)kq.y, false);
      f1 = __builtin_amdgcn_cvt_pk_f32_fp8((int)kq.y, true);
      kd += qd[4] * f0[0] + qd[5] * f0[1] + qd[6] * f1[0] + qd[7] * f1[1];
      f0 = __builtin_amdgcn_cvt_pk_f32_fp8((int)kq.z, false);
      f1 = __builtin_amdgcn_cvt_pk_f32_fp8((int)kq.z, true);
      kd += qd[8] * f0[0] + qd[9] * f0[1] + qd[10] * f1[0] + qd[11] * f1[1];
      f0 = __builtin_amdgcn_cvt_pk_f32_fp8((int)kq.w, false);
      f1 = __builtin_amdgcn_cvt_pk_f32_fp8((int)kq.w, true);
      kd += qd[12] * f0[0] + qd[13] * f0[1] + qd[14] * f1[0] + qd[15] * f1[1];
    }
    float pe = __expf(kd + ed);
    lsum += pe;
    {
      fx2 g0, g1;
      g0 = __builtin_amdgcn_cvt_pk_f32_fp8((int)vq.x, false);
      g1 = __builtin_amdgcn_cvt_pk_f32_fp8((int)vq.x, true);
      acc[0] += pe * g0[0]; acc[1] += pe * g0[1]; acc[2] += pe * g1[0]; acc[3] += pe * g1[1];
      g0 = __builtin_amdgcn_cvt_pk_f32_fp8((int)vq.y, false);
      g1 = __builtin_amdgcn_cvt_pk_f32_fp8((int)vq.y, true);
      acc[4] += pe * g0[0]; acc[5] += pe * g0[1]; acc[6] += pe * g1[0]; acc[7] += pe * g1[1];
      g0 = __builtin_amdgcn_cvt_pk_f32_fp8((int)vq.z, false);
      g1 = __builtin_amdgcn_cvt_pk_f32_fp8((int)vq.z, true);
      acc[8] += pe * g0[0]; acc[9] += pe * g0[1]; acc[10] += pe * g1[0]; acc[11] += pe * g1[1];
      g0 = __builtin_amdgcn_cvt_pk_f32_fp8((int)vq.w, false);
      g1 = __builtin_amdgcn_cvt_pk_f32_fp8((int)vq.w, true);
      acc[12] += pe * g0[0]; acc[13] += pe * g0[1]; acc[14] += pe * g1[0]; acc[15] += pe * g1[1];
    }
  };
  dopass(kq0, vq0, ed0);
  dopass(kq1, vq1, ed1);
  dopass(kq2, vq2, ed2);
  dopass(kq3, vq3, ed3);

  lsum += __shfl_xor(lsum, 8, 64);
  lsum += __shfl_xor(lsum, 16, 64);
  lsum += __shfl_xor(lsum, 32, 64);

  float r8[8];
  const bool hiA = (l & 32) != 0;
#pragma unroll
  for (int i = 0; i < 8; i++) {
    float keep = hiA ? acc[i + 8] : acc[i];
    float send = hiA ? acc[i]     : acc[i + 8];
    r8[i] = keep + __shfl_xor(send, 32, 64);
  }
  float r4[4];
  const bool hiB = (l & 16) != 0;
#pragma unroll
  for (int i = 0; i < 4; i++) {
    float keep = hiB ? r8[i + 4] : r8[i];
    float send = hiB ? r8[i]     : r8[i + 4];
    r4[i] = keep + __shfl_xor(send, 16, 64);
  }
  float r2[2];
  const bool hiC = (l & 8) != 0;
#pragma unroll
  for (int i = 0; i < 2; i++) {
    float keep = hiC ? r4[i + 2] : r4[i];
    float send = hiC ? r4[i]     : r4[i + 2];
    r2[i] = keep + __shfl_xor(send, 8, 64);
  }
  float inv = 1.f / (lsum + 1e-16f);
  unsigned o16 = (unsigned)f2bf_bits(r2[0] * inv) | ((unsigned)f2bf_bits(r2[1] * inv) << 16);
  *(unsigned*)(Agg16 + (size_t)q * 128 + h * 16 + 2 * j) = o16;
}

// ---------------- fused MLP: bf16 Agg input (direct short8 fragments, no cvt) ----------------
__global__ __launch_bounds__(256, 1) void mlp_kernel(
    const float* __restrict__ h_query, const unsigned short* __restrict__ Agg16,
    const unsigned short* __restrict__ W1p, const unsigned short* __restrict__ W2p,
    const float* __restrict__ b1, const float* __restrict__ b2,
    const float* __restrict__ gamma, const float* __restrict__ beta,
    float* __restrict__ out) {
  constexpr int M = N_QUERY;
  constexpr int STRIDE = 136;                  // ushorts per hid row (272 B)
  __shared__ unsigned short Wlds[16384];       // 32 KB rotating weight stage
  __shared__ unsigned short hid[64 * STRIDE];  // 17.4 KB hidden activations

  const int tid  = threadIdx.x;
  const int l    = tid & 63;
  const int w    = tid >> 6;
  const int quad = l >> 4;
  const int col0 = l & 15;
  const int row0 = blockIdx.x * 64 + w * 16;
  const int grow = row0 + col0;
  const int arow = grow < M ? grow : M - 1;

  // 1) issue A-rows: h_query (8 float4, tiles 0..3) + Agg16 (4 short8 fragments, tiles 4..7)
  const float* hp = h_query + (size_t)arow * 128 + quad * 8;
  const unsigned short* gp = Agg16 + (size_t)arow * 128;
  floatx4 a[8];
  short8 afg[4];
#pragma unroll
  for (int k0 = 0; k0 < 4; k0++) {
    a[2*k0]   = *(const floatx4*)(hp + k0 * 32);
    a[2*k0+1] = *(const floatx4*)(hp + k0 * 32 + 4);
    afg[k0]   = *(const short8*)(gp + k0 * 32 + quad * 8);
  }

  // 2) stage W1 k-tiles 0..3 (k0 < 128): 32 KB coalesced
  {
    const uint4* gsrc = (const uint4*)W1p;
    uint4* ldst = (uint4*)Wlds;
#pragma unroll
    for (int it = 0; it < 8; it++) ldst[it * 256 + tid] = gsrc[it * 256 + tid];
  }

  // 3) convert h_query half to bf16 fragments (Agg half is already bf16)
  short8 af[4];
#pragma unroll
  for (int t = 0; t < 4; t++) {
    af[t][0] = (short)f2bf_bits(a[2*t][0]);   af[t][1] = (short)f2bf_bits(a[2*t][1]);
    af[t][2] = (short)f2bf_bits(a[2*t][2]);   af[t][3] = (short)f2bf_bits(a[2*t][3]);
    af[t][4] = (short)f2bf_bits(a[2*t+1][0]); af[t][5] = (short)f2bf_bits(a[2*t+1][1]);
    af[t][6] = (short)f2bf_bits(a[2*t+1][2]); af[t][7] = (short)f2bf_bits(a[2*t+1][3]);
  }
  __syncthreads();

  // 4) GEMM1 first half (k0 < 128)
  floatx4 acc[8];
#pragma unroll
  for (int i = 0; i < 8; i++) acc[i] = (floatx4){0.f, 0.f, 0.f, 0.f};
#pragma unroll
  for (int kt = 0; kt < 4; kt++) {
    const unsigned short* bbase = Wlds + kt * 4096 + l * 8;
#pragma unroll
    for (int nt = 0; nt < 8; nt++) {
      short8 bf = *(const short8*)(bbase + nt * 512);
      acc[nt] = __builtin_amdgcn_mfma_f32_16x16x32_bf16(bf, af[kt], acc[nt], 0, 0, 0);
    }
  }
  __syncthreads();

  // 5) stage W1 k-tiles 4..7 (k0 >= 128)
  {
    const uint4* gsrc = (const uint4*)(W1p + 16384);
    uint4* ldst = (uint4*)Wlds;
#pragma unroll
    for (int it = 0; it < 8; it++) ldst[it * 256 + tid] = gsrc[it * 256 + tid];
  }
  __syncthreads();

  // 6) GEMM1 second half (A = Agg16 fragments, already bf16)
#pragma unroll
  for (int kt = 0; kt < 4; kt++) {
    const unsigned short* bbase = Wlds + kt * 4096 + l * 8;
#pragma unroll
    for (int nt = 0; nt < 8; nt++) {
      short8 bf = *(const short8*)(bbase + nt * 512);
      acc[nt] = __builtin_amdgcn_mfma_f32_16x16x32_bf16(bf, afg[kt], acc[nt], 0, 0, 0);
    }
  }

  // 7) hidden -> LDS (bias + relu, bf16, 8-B stores)
  {
    const int rl = w * 16 + col0;
#pragma unroll
    for (int nt = 0; nt < 8; nt++) {
      const int c = nt * 16 + quad * 4;
      float4 bb = *(const float4*)(b1 + c);
      unsigned u0 = (unsigned)f2bf_bits(fmaxf(acc[nt][0] + bb.x, 0.f))
                  | ((unsigned)f2bf_bits(fmaxf(acc[nt][1] + bb.y, 0.f)) << 16);
      unsigned u1 = (unsigned)f2bf_bits(fmaxf(acc[nt][2] + bb.z, 0.f))
                  | ((unsigned)f2bf_bits(fmaxf(acc[nt][3] + bb.w, 0.f)) << 16);
      uint2 uu; uu.x = u0; uu.y = u1;
      *(uint2*)(hid + rl * STRIDE + c) = uu;
    }
  }
  __syncthreads();

  // 8) stage W2 (32 KB)
  {
    const uint4* gsrc = (const uint4*)W2p;
    uint4* ldst = (uint4*)Wlds;
#pragma unroll
    for (int it = 0; it < 8; it++) ldst[it * 256 + tid] = gsrc[it * 256 + tid];
  }
  __syncthreads();

  // 9) GEMM2 (K=128), A from hid, B from Wlds
  floatx4 acc2[8];
#pragma unroll
  for (int i = 0; i < 8; i++) acc2[i] = (floatx4){0.f, 0.f, 0.f, 0.f};
  const int rloc = w * 16 + col0;
#pragma unroll
  for (int k0 = 0; k0 < 128; k0 += 32) {
    short8 af2 = *(const short8*)(hid + rloc * STRIDE + k0 + quad * 8);
    const unsigned short* bbase = Wlds + (k0 >> 5) * 4096 + l * 8;
#pragma unroll
    for (int nt = 0; nt < 8; nt++) {
      short8 bf = *(const short8*)(bbase + nt * 512);
      acc2[nt] = __builtin_amdgcn_mfma_f32_16x16x32_bf16(bf, af2, acc2[nt], 0, 0, 0);
    }
  }

  // 10) residual + LayerNorm: lane owns 32 channels of ONE row, reduce over quad
  const int rr = grow < M ? grow : M - 1;
  float v[8][4];
  float s1 = 0.f, s2 = 0.f;
#pragma unroll
  for (int nt = 0; nt < 8; nt++) {
    const int c = nt * 16 + quad * 4;
    float4 hq = *(const float4*)(h_query + (size_t)rr * 128 + c);
    float4 bb = *(const float4*)(b2 + c);
    float t0 = acc2[nt][0] + bb.x + hq.x;
    float t1 = acc2[nt][1] + bb.y + hq.y;
    float t2 = acc2[nt][2] + bb.z + hq.z;
    float t3 = acc2[nt][3] + bb.w + hq.w;
    v[nt][0] = t0; v[nt][1] = t1; v[nt][2] = t2; v[nt][3] = t3;
    s1 += t0 + t1 + t2 + t3;
    s2 += t0 * t0 + t1 * t1 + t2 * t2 + t3 * t3;
  }
  s1 += __shfl_xor(s1, 16, 64); s1 += __shfl_xor(s1, 32, 64);
  s2 += __shfl_xor(s2, 16, 64); s2 += __shfl_xor(s2, 32, 64);
  float mean = s1 * (1.0f / 128.0f);
  float var  = s2 * (1.0f / 128.0f) - mean * mean;
  float rstd = rsqrtf(var + 1e-5f);
  if (grow < M) {
#pragma unroll
    for (int nt = 0; nt < 8; nt++) {
      const int c = nt * 16 + quad * 4;
      float4 gg = *(const float4*)(gamma + c);
      float4 be = *(const float4*)(beta + c);
      float4 o;
      o.x = (v[nt][0] - mean) * rstd * gg.x + be.x;
      o.y = (v[nt][1] - mean) * rstd * gg.y + be.y;
      o.z = (v[nt][2] - mean) * rstd * gg.z + be.z;
      o.w = (v[nt][3] - mean) * rstd * gg.w + be.w;
      *(float4*)(out + (size_t)grow * 128 + c) = o;
    }
  }
}

extern "C" void kernel_launch(void* const* d_in, const int* in_sizes, int n_in,
                              void* d_out, int out_size, void* d_ws, size_t ws_size,
                              hipStream_t stream) {
  const float* h_atom    = (const float*)d_in[0];
  const float* h_query   = (const float*)d_in[1];
  const float* edge_attr = (const float*)d_in[2];
  const float* W_q  = (const float*)d_in[3];
  const float* W_k  = (const float*)d_in[4];
  const float* W_v  = (const float*)d_in[5];
  const float* Wrbf = (const float*)d_in[6];
  const float* W1   = (const float*)d_in[7];
  const float* b1   = (const float*)d_in[8];
  const float* W2   = (const float*)d_in[9];
  const float* b2   = (const float*)d_in[10];
  const float* ln_g = (const float*)d_in[11];
  const float* ln_b = (const float*)d_in[12];
  const int* edge_index = (const int*)d_in[13];   // [0..E) = src
  float* out = (float*)d_out;

  char* ws = (char*)d_ws;
  unsigned char*  Kp8  = (unsigned char*)(ws);                 // 12.8 MB
  unsigned char*  Vp8  = (unsigned char*)(ws + 12800000);      // 12.8 MB
  unsigned short* Qb   = (unsigned short*)(ws + 25600000);     // 5.12 MB
  unsigned short* Agg16= (unsigned short*)(ws + 30720000);     // 20000*128 bf16 = 5.12 MB
  unsigned short* WKVp = (unsigned short*)(ws + 40960000);     // 128x256
  unsigned short* WQp  = WKVp + 32768;                         // 128x128
  unsigned short* W1p  = WQp  + 16384;                         // 256x128
  unsigned short* W2p  = W1p  + 32768;                         // 128x128
  float* ED            = (float*)(ws + 41160704);              // 640000*8 f32 = 20.48 MB

  // pack weights only (384 blocks, ~3 us)
  pack_all_kernel<<<(98304 + 255) / 256, 256, 0, stream>>>(
      W_q, W_k, W_v, W1, W2, WKVp, WQp, W1p, W2p);

  // merged KV/Q projection + ED streaming blocks
  constexpr int KB  = (N_ATOM + 63) / 64;    // 1563
  constexpr int QB  = (N_QUERY + 63) / 64;   // 313
  constexpr int EDB = 1280;
  gemm_kvq<<<KB + QB + EDB, 256, 0, stream>>>(
      h_atom, h_query, WKVp, WQp, edge_attr, Wrbf, Kp8, Vp8, Qb, ED);

  // attention -> Agg16 (bf16)
  attn_kernel<<<N_QUERY / 4, 256, 0, stream>>>(Qb, Kp8, Vp8, ED, edge_index, Agg16);

  // fused MLP + residual + LayerNorm -> out
  mlp_kernel<<<(N_QUERY + 63) / 64, 256, 0, stream>>>(
      h_query, Agg16, W1p, W2p, b1, b2, ln_g, ln_b, out);
}